// Round 5
// baseline (6934.282 us; speedup 1.0000x reference)
//
#include <hip/hip_runtime.h>
#include <math.h>

#define N_IN   65536
#define N_UP   262144
#define N_OUT  131072
#define C_IN   128
#define C_OUT  64
#define K1     27
#define K2     27
#define K3     16
#define EPSV   1e-6f
#define TSHIFT 8            // 256-row output tiles

// ---------------------------------------------------------------------------
// Pass A: histogram pairs into (dst-block, k) bins.
template <int KNUM, int MSHIFT>
__global__ __launch_bounds__(256) void hist_kernel(
    const int* __restrict__ kout, int* __restrict__ hist)
{
    const int n = KNUM << MSHIFT;
    for (int j = blockIdx.x * 256 + threadIdx.x; j < n; j += gridDim.x * 256) {
        const int k = j >> MSHIFT;
        const int b = kout[j] >> TSHIFT;
        atomicAdd(hist + b * KNUM + k, 1);
    }
}

// Pass B: single-block exclusive scan over nbins bins -> offs[nbins+1], cursor.
__global__ __launch_bounds__(1024) void scan_kernel(
    const int* __restrict__ hist, int* __restrict__ offs,
    int* __restrict__ cursor, int nbins)
{
    __shared__ int ps[1024];
    const int t = threadIdx.x;
    const int per = (nbins + 1023) >> 10;
    const int base = t * per;
    int s = 0;
    for (int i = 0; i < per; ++i) {
        const int b = base + i;
        if (b < nbins) s += hist[b];
    }
    ps[t] = s;
    __syncthreads();
    for (int off = 1; off < 1024; off <<= 1) {
        const int v = (t >= off) ? ps[t - off] : 0;
        __syncthreads();
        ps[t] += v;
        __syncthreads();
    }
    int run = (t == 0) ? 0 : ps[t - 1];
    for (int i = 0; i < per; ++i) {
        const int b = base + i;
        if (b < nbins) {
            const int h = hist[b];
            offs[b] = run;
            cursor[b] = run;
            run += h;
        }
    }
    if (t == 1023) offs[nbins] = run;
}

// Pass C: scatter pairs to sorted positions. word = (dst & 255)<<18 | src.
template <int KNUM, int MSHIFT>
__global__ __launch_bounds__(256) void scatter_kernel(
    const int* __restrict__ kin, const int* __restrict__ kout,
    int* __restrict__ cursor, unsigned* __restrict__ sorted)
{
    const int n = KNUM << MSHIFT;
    for (int j = blockIdx.x * 256 + threadIdx.x; j < n; j += gridDim.x * 256) {
        const int k   = j >> MSHIFT;
        const int dst = kout[j];
        const int b   = dst >> TSHIFT;
        const int pos = atomicAdd(cursor + b * KNUM + k, 1);
        sorted[pos] = (unsigned)kin[j] |
                      ((unsigned)(dst & ((1 << TSHIFT) - 1)) << 18);
    }
}

// ---------------------------------------------------------------------------
// Output-stationary conv, half-channel pass (h = 0/1 -> out channels h*32..+32).
// Workgroup owns a 256-row x 32-ch tile in LDS. Each wave walks k = wv,wv+4,...
// Weights: W[k]'s 32-ch slice staged in a PRIVATE per-wave LDS buffer (8KB)
// once per k-segment; the FMA broadcast operand comes from uniform-address
// ds_read_b128 (HW broadcast, conflict-free) -- no per-batch scalar-load
// streams (those thrashed sK$ and stalled 70%+ of cycles in r2/r4).
// Cross-batch pipeline: next batch's word + x-chunks 0,1 issue before the
// LDS scatter. CIN=128 runs 2 ci-sweeps (wbuf holds 64 ci at a time).
// Epilogue: coalesced stores + fused per-channel sum/sumsq -> stats atomics.
template <int CIN, int KNUM>
__global__ __launch_bounds__(256) void conv_tile(
    const float* __restrict__ X, const float* __restrict__ W,
    const unsigned* __restrict__ sorted, const int* __restrict__ offs,
    float* __restrict__ outp, float* __restrict__ stats,
    const int h, const int nx)
{
    __shared__ float tile[256][32];      // [r][(c + r) & 31]   32KB
    __shared__ float wbuf[4][64][32];    // per-wave W slice    32KB

    const int lane   = threadIdx.x & 63;
    const int wv     = threadIdx.x >> 6;
    const int bucket = blockIdx.x;
    constexpr int SWEEPS = CIN / 64;

    // zero tile
    {
        float4* tf = (float4*)&tile[0][0];
#pragma unroll
        for (int i = 0; i < 8; ++i)
            tf[threadIdx.x + 256 * i] = float4{0.f, 0.f, 0.f, 0.f};
    }
    __syncthreads();

    const int ci0 = lane >> 3;   // staging: 8 lanes per ci-row
    const int f4s = lane & 7;

    for (int sw = 0; sw < SWEEPS; ++sw) {
        int kcur = wv, bs = 0, e = 0;
        while (kcur < KNUM) {
            bs = offs[bucket * KNUM + kcur];
            e  = offs[bucket * KNUM + kcur + 1];
            if (bs < e) break;
            kcur += 4;
        }
        if (kcur >= KNUM) continue;

        // ---- stage W[kcur] slice: wbuf[wv][ci][c'] = W[k][sw*64+ci][h*32+c']
        {
            const float* Ws = W +
                ((size_t)__builtin_amdgcn_readfirstlane(kcur) * CIN + sw * 64) * 64 + h * 32;
#pragma unroll
            for (int it = 0; it < 8; ++it) {
                const int ci = it * 8 + ci0;
                float4 v = *(const float4*)(Ws + ci * 64 + f4s * 4);
                *(float4*)&wbuf[wv][ci][f4s * 4] = v;
            }
        }

        // ---- prologue: first batch word + chunks 0,1
        unsigned wcur = sorted[bs + lane];
        int src = (int)(wcur & 0x3FFFFu); src = src < nx ? src : nx - 1;
        const float4* xr = (const float4*)(X + (size_t)src * CIN) + sw * 16;
        float4 xa0 = xr[0], xa1 = xr[1], xa2 = xr[2], xa3 = xr[3];
        float4 xb0 = xr[4], xb1 = xr[5], xb2 = xr[6], xb3 = xr[7];

        while (true) {
            const int  rl    = (wcur >> 18) & 255;
            const bool valid = (bs + lane) < e;

            // find next batch (may cross k-segments)
            int kn = kcur, bn = bs + 64, en = e;
            while (bn >= en) {
                kn += 4;
                if (kn >= KNUM) break;
                bn = offs[bucket * KNUM + kn];
                en = offs[bucket * KNUM + kn + 1];
            }
            const bool have = (kn < KNUM);
            const unsigned wnxt = have ? sorted[bn + lane] : wcur;
            int srcn = (int)(wnxt & 0x3FFFFu); srcn = srcn < nx ? srcn : nx - 1;
            const float4* xrn = (const float4*)(X + (size_t)srcn * CIN) + sw * 16;

            float acc[32];
#pragma unroll
            for (int c = 0; c < 32; ++c) acc[c] = 0.f;

#pragma unroll
            for (int g = 0; g < 4; ++g) {
                // prefetch: this batch's chunk g+2, or next batch's chunk g-2
                float4 xc0, xc1, xc2, xc3;
                if (g < 2) {
                    xc0 = xr[(g + 2) * 4 + 0]; xc1 = xr[(g + 2) * 4 + 1];
                    xc2 = xr[(g + 2) * 4 + 2]; xc3 = xr[(g + 2) * 4 + 3];
                } else {
                    const int m = g - 2;
                    xc0 = xrn[m * 4 + 0]; xc1 = xrn[m * 4 + 1];
                    xc2 = xrn[m * 4 + 2]; xc3 = xrn[m * 4 + 3];
                }

                float xs[16];
                xs[0]=xa0.x; xs[1]=xa0.y; xs[2]=xa0.z; xs[3]=xa0.w;
                xs[4]=xa1.x; xs[5]=xa1.y; xs[6]=xa1.z; xs[7]=xa1.w;
                xs[8]=xa2.x; xs[9]=xa2.y; xs[10]=xa2.z; xs[11]=xa2.w;
                xs[12]=xa3.x; xs[13]=xa3.y; xs[14]=xa3.z; xs[15]=xa3.w;

#pragma unroll
                for (int i = 0; i < 16; ++i) {
                    const float xi = xs[i];
                    const float* wrow = &wbuf[wv][g * 16 + i][0];  // uniform addr
#pragma unroll
                    for (int q = 0; q < 8; ++q) {
                        const float4 wq = *(const float4*)(wrow + q * 4);
                        acc[q*4+0] = fmaf(xi, wq.x, acc[q*4+0]);
                        acc[q*4+1] = fmaf(xi, wq.y, acc[q*4+1]);
                        acc[q*4+2] = fmaf(xi, wq.z, acc[q*4+2]);
                        acc[q*4+3] = fmaf(xi, wq.w, acc[q*4+3]);
                    }
                }
                xa0 = xb0; xa1 = xb1; xa2 = xb2; xa3 = xb3;
                xb0 = xc0; xb1 = xc1; xb2 = xc2; xb3 = xc3;
            }
            // xa/xb now hold NEXT batch chunks 0,1 (loads in flight)

            if (valid) {
#pragma unroll
                for (int c = 0; c < 32; ++c)
                    atomicAdd(&tile[rl][(c + rl) & 31], acc[c]);
            }

            if (!have) break;
            if (kn != kcur) {            // k changed: restage weights
                kcur = kn;
                const float* Ws = W +
                    ((size_t)__builtin_amdgcn_readfirstlane(kcur) * CIN + sw * 64) * 64 + h * 32;
#pragma unroll
                for (int it = 0; it < 8; ++it) {
                    const int ci = it * 8 + ci0;
                    float4 v = *(const float4*)(Ws + ci * 64 + f4s * 4);
                    *(float4*)&wbuf[wv][ci][f4s * 4] = v;
                }
            }
            bs = bn; e = en;
            wcur = wnxt;
            xr = xrn;
        }
    }
    __syncthreads();

    // ---- epilogue: coalesced stores + fused per-channel stats
    const int c  = threadIdx.x & 31;
    const int rg = threadIdx.x >> 5;     // 8 groups of 32 rows
    float s = 0.f, s2 = 0.f;
#pragma unroll
    for (int j = 0; j < 32; ++j) {
        const int r = rg * 32 + j;
        const float v = tile[r][(c + r) & 31];
        s += v;
        s2 = fmaf(v, v, s2);
        outp[((size_t)(bucket << TSHIFT) + r) * 64 + h * 32 + c] = v;
    }
    __syncthreads();
    float* shs  = (float*)&tile[0][0];   // reuse tile LDS (reads all done)
    float* shs2 = shs + 256;
    shs[rg * 32 + c]  = s;
    shs2[rg * 32 + c] = s2;
    __syncthreads();
    if (threadIdx.x < 32) {
        float ts = 0.f, ts2 = 0.f;
#pragma unroll
        for (int j = 0; j < 8; ++j) {
            ts  += shs[j * 32 + threadIdx.x];
            ts2 += shs2[j * 32 + threadIdx.x];
        }
        atomicAdd(stats + h * 32 + threadIdx.x, ts);
        atomicAdd(stats + 64 + h * 32 + threadIdx.x, ts2);
    }
}

// ---------------------------------------------------------------------------
// stats[128+c]=mean, stats[192+c]=rsqrt(var+eps)
__global__ void finalize_stats(float* stats, float inv_n)
{
    const int c = threadIdx.x;   // 64 threads
    float mu  = stats[c] * inv_n;
    float var = stats[64 + c] * inv_n - mu * mu;
    stats[128 + c] = mu;
    stats[192 + c] = rsqrtf(var + EPSV);
}

// x = elu((x-mu)*scale) (+ fp32 encoder skip if enc != null), in place.
__global__ __launch_bounds__(256) void norm_elu(
    float* __restrict__ x, const float* __restrict__ stats,
    const float* __restrict__ enc)
{
    const int i = blockIdx.x * 256 + threadIdx.x;
    const int c = i & 63;
    float v = (x[i] - stats[128 + c]) * stats[192 + c];
    v = (v > 0.f) ? v : expm1f(v);
    if (enc) v += enc[i];
    x[i] = v;
}

// Final: normalize+elu, pruning dot, keep mask, fp32 outputs.
__global__ __launch_bounds__(256) void final_kernel(
    const float* __restrict__ x, const float* __restrict__ stats,
    const float* __restrict__ Wp, const float* __restrict__ bp,
    float* __restrict__ outp)
{
    const int lane = threadIdx.x & 63;
    const int wid  = threadIdx.x >> 6;
    const int row  = blockIdx.x * 4 + wid;

    float v = (x[(size_t)row * 64 + lane] - stats[128 + lane]) * stats[192 + lane];
    v = (v > 0.f) ? v : expm1f(v);

    float p = v * Wp[lane];
#pragma unroll
    for (int m = 1; m < 64; m <<= 1)
        p += __shfl_xor(p, m, 64);
    p += bp[0];

    const bool keep = p > 0.0f;
    outp[(size_t)row * 64 + lane] = keep ? v : 0.f;
    if (lane == 0)
        outp[(size_t)N_OUT * 64 + row] = keep ? 1.f : 0.f;
}

extern "C" void kernel_launch(void* const* d_in, const int* in_sizes, int n_in,
                              void* d_out, int out_size, void* d_ws, size_t ws_size,
                              hipStream_t stream)
{
    const float* in_feats = (const float*)d_in[0];   // [65536,128] f32
    const float* enc      = (const float*)d_in[1];   // [262144,64] f32
    const float* W1       = (const float*)d_in[2];   // [27,128,64] f32
    const float* W2       = (const float*)d_in[3];   // [27,64,64]  f32
    const float* W3       = (const float*)d_in[4];   // [16,64,64]  f32
    const float* Wp       = (const float*)d_in[5];   // [64,1] f32
    const float* bp       = (const float*)d_in[6];   // [1] f32
    const int* kin1  = (const int*)d_in[7];
    const int* kout1 = (const int*)d_in[8];
    const int* kin2  = (const int*)d_in[9];
    const int* kout2 = (const int*)d_in[10];
    const int* kin3  = (const int*)d_in[11];
    const int* kout3 = (const int*)d_in[12];
    float* outp = (float*)d_out;

    // Workspace: within the proven 128MB+stats footprint.
    char* ws = (char*)d_ws;
    float* up_a   = (float*)ws;                      // 64 MB [262144,64]
    float* up_b   = (float*)(ws + 67108864);         // 64 MB [262144,64]
    float* out3   = up_a;                            // 32 MB reuse after conv2
    float* statsA = (float*)(ws + 134217728);        // 256 f32 each
    float* statsB = statsA + 256;
    float* statsC = statsA + 512;

    // Sort scratch in d_out (>= 34MB, dead until final_kernel overwrites it).
    char* scratch = (char*)d_out;
    unsigned* sorted = (unsigned*)scratch;               // [0, 16MB)
    int* hist   = (int*)(scratch + 16777216);
    int* offs   = (int*)(scratch + 16908288);
    int* cursor = (int*)(scratch + 17039360);

    const int NBK1 = N_UP  >> TSHIFT;   // 1024 buckets
    const int NBK3 = N_OUT >> TSHIFT;   // 512 buckets
    const int NB1  = NBK1 * K1;         // 27648 bins
    const int NB3  = NBK3 * K3;         // 8192 bins

    (void)hipMemsetAsync(statsA, 0, 3 * 256 * 4, stream);

    // ---- dec_block_1a: conv-transpose (input_feats -> up_a), CIN=128
    (void)hipMemsetAsync(hist, 0, NB1 * 4, stream);
    hist_kernel<K1, 16><<<1024, 256, 0, stream>>>(kout1, hist);
    scan_kernel<<<1, 1024, 0, stream>>>(hist, offs, cursor, NB1);
    scatter_kernel<K1, 16><<<1024, 256, 0, stream>>>(kin1, kout1, cursor, sorted);
    conv_tile<128, K1><<<NBK1, 256, 0, stream>>>(in_feats, W1, sorted, offs, up_a, statsA, 0, N_IN);
    conv_tile<128, K1><<<NBK1, 256, 0, stream>>>(in_feats, W1, sorted, offs, up_a, statsA, 1, N_IN);
    finalize_stats<<<1, 64, 0, stream>>>(statsA, 1.f / N_UP);
    norm_elu<<<(N_UP * 64) / 256, 256, 0, stream>>>(up_a, statsA, nullptr);

    // ---- dec_block_1b: conv 3x3x3 (up_a -> up_b), CIN=64
    (void)hipMemsetAsync(hist, 0, NB1 * 4, stream);
    hist_kernel<K2, 17><<<1024, 256, 0, stream>>>(kout2, hist);
    scan_kernel<<<1, 1024, 0, stream>>>(hist, offs, cursor, NB1);
    scatter_kernel<K2, 17><<<1024, 256, 0, stream>>>(kin2, kout2, cursor, sorted);
    conv_tile<64, K2><<<NBK1, 256, 0, stream>>>(up_a, W2, sorted, offs, up_b, statsB, 0, N_UP);
    conv_tile<64, K2><<<NBK1, 256, 0, stream>>>(up_a, W2, sorted, offs, up_b, statsB, 1, N_UP);
    finalize_stats<<<1, 64, 0, stream>>>(statsB, 1.f / N_UP);
    norm_elu<<<(N_UP * 64) / 256, 256, 0, stream>>>(up_b, statsB, enc);  // + skip

    // ---- dec_block_2: conv k=2 (up_b -> out3), CIN=64
    (void)hipMemsetAsync(hist, 0, NB3 * 4, stream);
    hist_kernel<K3, 17><<<1024, 256, 0, stream>>>(kout3, hist);
    scan_kernel<<<1, 1024, 0, stream>>>(hist, offs, cursor, NB3);
    scatter_kernel<K3, 17><<<1024, 256, 0, stream>>>(kin3, kout3, cursor, sorted);
    conv_tile<64, K3><<<NBK3, 256, 0, stream>>>(up_b, W3, sorted, offs, out3, statsC, 0, N_UP);
    conv_tile<64, K3><<<NBK3, 256, 0, stream>>>(up_b, W3, sorted, offs, out3, statsC, 1, N_UP);
    finalize_stats<<<1, 64, 0, stream>>>(statsC, 1.f / N_OUT);

    // ---- pruning head + fp32 outputs (overwrites all scratch in d_out)
    final_kernel<<<N_OUT / 4, 256, 0, stream>>>(out3, statsC, Wp, bp, outp);
}

// Round 6
// 5548.486 us; speedup vs baseline: 1.2498x; 1.2498x over previous
//
#include <hip/hip_runtime.h>
#include <math.h>

#define N_IN   65536
#define N_UP   262144
#define N_OUT  131072
#define C_IN   128
#define C_OUT  64
#define K1     27
#define K2     27
#define K3     16
#define EPSV   1e-6f
#define TSHIFT 7            // 128-row output tiles (32KB tile + 16KB xbuf LDS)

// ---------------------------------------------------------------------------
// Pass A: histogram pairs into (dst-block, k) bins.
template <int KNUM, int MSHIFT>
__global__ __launch_bounds__(256) void hist_kernel(
    const int* __restrict__ kout, int* __restrict__ hist)
{
    const int n = KNUM << MSHIFT;
    for (int j = blockIdx.x * 256 + threadIdx.x; j < n; j += gridDim.x * 256) {
        const int k = j >> MSHIFT;
        const int b = kout[j] >> TSHIFT;
        atomicAdd(hist + b * KNUM + k, 1);
    }
}

// Pass B: single-block exclusive scan over nbins bins -> offs[nbins+1], cursor.
__global__ __launch_bounds__(1024) void scan_kernel(
    const int* __restrict__ hist, int* __restrict__ offs,
    int* __restrict__ cursor, int nbins)
{
    __shared__ int ps[1024];
    const int t = threadIdx.x;
    const int per = (nbins + 1023) >> 10;
    const int base = t * per;
    int s = 0;
    for (int i = 0; i < per; ++i) {
        const int b = base + i;
        if (b < nbins) s += hist[b];
    }
    ps[t] = s;
    __syncthreads();
    for (int off = 1; off < 1024; off <<= 1) {
        const int v = (t >= off) ? ps[t - off] : 0;
        __syncthreads();
        ps[t] += v;
        __syncthreads();
    }
    int run = (t == 0) ? 0 : ps[t - 1];
    for (int i = 0; i < per; ++i) {
        const int b = base + i;
        if (b < nbins) {
            const int h = hist[b];
            offs[b] = run;
            cursor[b] = run;
            run += h;
        }
    }
    if (t == 1023) offs[nbins] = run;
}

// Pass C: scatter pairs to sorted positions. word = (dst & 127)<<18 | src.
template <int KNUM, int MSHIFT>
__global__ __launch_bounds__(256) void scatter_kernel(
    const int* __restrict__ kin, const int* __restrict__ kout,
    int* __restrict__ cursor, unsigned* __restrict__ sorted)
{
    const int n = KNUM << MSHIFT;
    for (int j = blockIdx.x * 256 + threadIdx.x; j < n; j += gridDim.x * 256) {
        const int k   = j >> MSHIFT;
        const int dst = kout[j];
        const int b   = dst >> TSHIFT;
        const int pos = atomicAdd(cursor + b * KNUM + k, 1);
        sorted[pos] = (unsigned)kin[j] |
                      ((unsigned)(dst & ((1 << TSHIFT) - 1)) << 18);
    }
}

// ---------------------------------------------------------------------------
// Weight-stationary output-tile conv.
//   block = 128-row bucket; tile[128][64] in LDS, ds_add accumulation.
//   wave wv walks k = wv, wv+4, ... independently (no inter-wave sync).
//   Weights: W[k][ci][lane] -> 64 VGPRs per wave (coalesced loads, reused
//     across the whole segment). NO per-FMA weight traffic (r2/r4 streamed
//     16KB/batch through sK$; r5 streamed 1 ds_read per 4 FMAs).
//   x: consumed once -> staged per 8-pair chunk into wave-private LDS
//     (double-buffered; global loads for chunk n+1 issued before computing
//     chunk n), then broadcast via uniform-address ds_read_b128.
//   Per pair: 64 FMA + 16 uniform ds_read + 1 ds_add_f32 (row uniform,
//     lane*4B -> 2 lanes/bank, conflict-free). Whole-wave sequential pairs:
//     no exec underfill, wave-uniform branches, zero global float atomics.
//   Epilogue: coalesced tile store + fused per-channel sum/sumsq.
template <int CIN, int KNUM>
__global__ __launch_bounds__(256, 3) void conv_tile(
    const float* __restrict__ X, const float* __restrict__ W,
    const unsigned* __restrict__ sorted, const int* __restrict__ offs,
    float* __restrict__ outp, float* __restrict__ stats)
{
    __shared__ float    tile[128][64];       // 32KB
    __shared__ float    xbuf[4][2][8][64];   // 16KB, wave-private slices
    __shared__ unsigned xw[4][2][8];         // staged pair words

    const int lane   = threadIdx.x & 63;
    const int wv     = threadIdx.x >> 6;
    const int bucket = blockIdx.x;
    const int pl     = lane >> 4;            // pair slot 0..3 (t adds 4)
    const int f16    = lane & 15;            // float4 slot within row
    constexpr int SW = CIN / 64;

    // zero tile: 8192 floats / 256 threads = 8 float4 each
    {
        float4* tf = (float4*)&tile[0][0];
#pragma unroll
        for (int i = 0; i < 8; ++i)
            tf[threadIdx.x + 256 * i] = float4{0.f, 0.f, 0.f, 0.f};
    }
    __syncthreads();

    for (int k = wv; k < KNUM; k += 4) {
        const int s = offs[bucket * KNUM + k];
        const int e = offs[bucket * KNUM + k + 1];
        if (s >= e) continue;

        for (int h = 0; h < SW; ++h) {
            // ---- weights into VGPRs: w[ci] = W[k][h*64+ci][lane]
            float w[64];
            const float* Wb = W + ((size_t)k * CIN + h * 64) * 64 + lane;
#pragma unroll
            for (int ci = 0; ci < 64; ++ci) w[ci] = Wb[ci * 64];

            const float* Xh = X + h * 64;

            float4 g0, g1; unsigned wd0, wd1;
#define STAGE_LOAD(CH) {                                                     \
            const int cb = s + (CH) * 8;                                     \
            int i0 = cb + pl;      i0 = i0 < e ? i0 : e - 1;                 \
            int i1 = cb + 4 + pl;  i1 = i1 < e ? i1 : e - 1;                 \
            wd0 = sorted[i0]; wd1 = sorted[i1];                              \
            g0 = *(const float4*)(Xh + (size_t)(wd0 & 0x3FFFFu) * CIN + f16 * 4); \
            g1 = *(const float4*)(Xh + (size_t)(wd1 & 0x3FFFFu) * CIN + f16 * 4); \
        }
#define STAGE_WRITE(B) {                                                     \
            *(float4*)&xbuf[wv][B][pl][f16 * 4]     = g0;                    \
            *(float4*)&xbuf[wv][B][4 + pl][f16 * 4] = g1;                    \
            if (f16 == 0) { xw[wv][B][pl] = wd0; xw[wv][B][4 + pl] = wd1; }  \
        }

            STAGE_LOAD(0)
            STAGE_WRITE(0)

            const int nch = (e - s + 7) >> 3;
            for (int ch = 0; ch < nch; ++ch) {
                const bool more = (ch + 1 < nch);
                if (more) STAGE_LOAD(ch + 1)     // loads in flight over compute

                const int cnt = (e - s - ch * 8) < 8 ? (e - s - ch * 8) : 8;
                const int b = ch & 1;
                for (int p = 0; p < cnt; ++p) {
                    const unsigned wrd = xw[wv][b][p];
                    const int rl = (wrd >> 18) & 127;
                    const float* xb = &xbuf[wv][b][p][0];

                    float4 xA0 = *(const float4*)(xb + 0);
                    float4 xA1 = *(const float4*)(xb + 4);
                    float4 xA2 = *(const float4*)(xb + 8);
                    float4 xA3 = *(const float4*)(xb + 12);
                    float a0 = 0.f, a1 = 0.f, a2 = 0.f, a3 = 0.f;
#pragma unroll
                    for (int q = 0; q < 4; ++q) {
                        float4 xB0, xB1, xB2, xB3;
                        if (q < 3) {   // read next quarter while FMAing this one
                            xB0 = *(const float4*)(xb + (q + 1) * 16 + 0);
                            xB1 = *(const float4*)(xb + (q + 1) * 16 + 4);
                            xB2 = *(const float4*)(xb + (q + 1) * 16 + 8);
                            xB3 = *(const float4*)(xb + (q + 1) * 16 + 12);
                        }
                        a0 = fmaf(xA0.x, w[q * 16 + 0], a0);
                        a1 = fmaf(xA0.y, w[q * 16 + 1], a1);
                        a2 = fmaf(xA0.z, w[q * 16 + 2], a2);
                        a3 = fmaf(xA0.w, w[q * 16 + 3], a3);
                        a0 = fmaf(xA1.x, w[q * 16 + 4], a0);
                        a1 = fmaf(xA1.y, w[q * 16 + 5], a1);
                        a2 = fmaf(xA1.z, w[q * 16 + 6], a2);
                        a3 = fmaf(xA1.w, w[q * 16 + 7], a3);
                        a0 = fmaf(xA2.x, w[q * 16 + 8], a0);
                        a1 = fmaf(xA2.y, w[q * 16 + 9], a1);
                        a2 = fmaf(xA2.z, w[q * 16 + 10], a2);
                        a3 = fmaf(xA2.w, w[q * 16 + 11], a3);
                        a0 = fmaf(xA3.x, w[q * 16 + 12], a0);
                        a1 = fmaf(xA3.y, w[q * 16 + 13], a1);
                        a2 = fmaf(xA3.z, w[q * 16 + 14], a2);
                        a3 = fmaf(xA3.w, w[q * 16 + 15], a3);
                        xA0 = xB0; xA1 = xB1; xA2 = xB2; xA3 = xB3;
                    }
                    const float tot = (a0 + a1) + (a2 + a3);
                    atomicAdd(&tile[rl][lane], tot);   // ds_add_f32, uniform row
                }
                if (more) STAGE_WRITE((ch + 1) & 1)    // vmcnt wait inserted here
            }
#undef STAGE_LOAD
#undef STAGE_WRITE
        }
    }
    __syncthreads();

    // ---- epilogue: coalesced stores + fused per-channel stats
    const int c  = threadIdx.x & 63;
    const int rg = threadIdx.x >> 6;         // 4 groups of 32 rows
    float sm = 0.f, s2 = 0.f;
#pragma unroll
    for (int j = 0; j < 32; ++j) {
        const int r = rg * 32 + j;
        const float v = tile[r][c];
        sm += v;
        s2 = fmaf(v, v, s2);
        outp[((size_t)(bucket << TSHIFT) + r) * 64 + c] = v;
    }
    __syncthreads();
    float* shs  = &tile[0][0];               // reuse tile LDS
    float* shs2 = shs + 256;
    shs[rg * 64 + c]  = sm;
    shs2[rg * 64 + c] = s2;
    __syncthreads();
    if (threadIdx.x < 64) {
        float ts = 0.f, ts2 = 0.f;
#pragma unroll
        for (int j = 0; j < 4; ++j) {
            ts  += shs[j * 64 + threadIdx.x];
            ts2 += shs2[j * 64 + threadIdx.x];
        }
        atomicAdd(stats + threadIdx.x, ts);
        atomicAdd(stats + 64 + threadIdx.x, ts2);
    }
}

// ---------------------------------------------------------------------------
// stats[128+c]=mean, stats[192+c]=rsqrt(var+eps)
__global__ void finalize_stats(float* stats, float inv_n)
{
    const int c = threadIdx.x;   // 64 threads
    float mu  = stats[c] * inv_n;
    float var = stats[64 + c] * inv_n - mu * mu;
    stats[128 + c] = mu;
    stats[192 + c] = rsqrtf(var + EPSV);
}

// x = elu((x-mu)*scale) (+ fp32 encoder skip if enc != null), in place.
__global__ __launch_bounds__(256) void norm_elu(
    float* __restrict__ x, const float* __restrict__ stats,
    const float* __restrict__ enc)
{
    const int i = blockIdx.x * 256 + threadIdx.x;
    const int c = i & 63;
    float v = (x[i] - stats[128 + c]) * stats[192 + c];
    v = (v > 0.f) ? v : expm1f(v);
    if (enc) v += enc[i];
    x[i] = v;
}

// Final: normalize+elu, pruning dot, keep mask, fp32 outputs.
__global__ __launch_bounds__(256) void final_kernel(
    const float* __restrict__ x, const float* __restrict__ stats,
    const float* __restrict__ Wp, const float* __restrict__ bp,
    float* __restrict__ outp)
{
    const int lane = threadIdx.x & 63;
    const int wid  = threadIdx.x >> 6;
    const int row  = blockIdx.x * 4 + wid;

    float v = (x[(size_t)row * 64 + lane] - stats[128 + lane]) * stats[192 + lane];
    v = (v > 0.f) ? v : expm1f(v);

    float p = v * Wp[lane];
#pragma unroll
    for (int m = 1; m < 64; m <<= 1)
        p += __shfl_xor(p, m, 64);
    p += bp[0];

    const bool keep = p > 0.0f;
    outp[(size_t)row * 64 + lane] = keep ? v : 0.f;
    if (lane == 0)
        outp[(size_t)N_OUT * 64 + row] = keep ? 1.f : 0.f;
}

extern "C" void kernel_launch(void* const* d_in, const int* in_sizes, int n_in,
                              void* d_out, int out_size, void* d_ws, size_t ws_size,
                              hipStream_t stream)
{
    const float* in_feats = (const float*)d_in[0];   // [65536,128] f32
    const float* enc      = (const float*)d_in[1];   // [262144,64] f32
    const float* W1       = (const float*)d_in[2];   // [27,128,64] f32
    const float* W2       = (const float*)d_in[3];   // [27,64,64]  f32
    const float* W3       = (const float*)d_in[4];   // [16,64,64]  f32
    const float* Wp       = (const float*)d_in[5];   // [64,1] f32
    const float* bp       = (const float*)d_in[6];   // [1] f32
    const int* kin1  = (const int*)d_in[7];
    const int* kout1 = (const int*)d_in[8];
    const int* kin2  = (const int*)d_in[9];
    const int* kout2 = (const int*)d_in[10];
    const int* kin3  = (const int*)d_in[11];
    const int* kout3 = (const int*)d_in[12];
    float* outp = (float*)d_out;

    // Workspace: within the proven 128MB+stats footprint.
    char* ws = (char*)d_ws;
    float* up_a   = (float*)ws;                      // 64 MB [262144,64]
    float* up_b   = (float*)(ws + 67108864);         // 64 MB [262144,64]
    float* out3   = up_a;                            // 32 MB reuse after conv2
    float* statsA = (float*)(ws + 134217728);        // 256 f32 each
    float* statsB = statsA + 256;
    float* statsC = statsA + 512;

    // Sort scratch in d_out (34MB total; dead until final_kernel overwrites).
    char* scratch = (char*)d_out;
    unsigned* sorted = (unsigned*)scratch;               // [0, 16MB)
    int* hist   = (int*)(scratch + 16777216);            // 256KB slot
    int* offs   = (int*)(scratch + 17039360);            // 256KB slot
    int* cursor = (int*)(scratch + 17301504);            // 256KB slot -> 17.6MB

    const int NBK1 = N_UP  >> TSHIFT;   // 2048 buckets
    const int NBK3 = N_OUT >> TSHIFT;   // 1024 buckets
    const int NB1  = NBK1 * K1;         // 55296 bins
    const int NB3  = NBK3 * K3;         // 16384 bins

    (void)hipMemsetAsync(statsA, 0, 3 * 256 * 4, stream);

    // ---- dec_block_1a: conv-transpose (input_feats -> up_a), CIN=128
    (void)hipMemsetAsync(hist, 0, NB1 * 4, stream);
    hist_kernel<K1, 16><<<1024, 256, 0, stream>>>(kout1, hist);
    scan_kernel<<<1, 1024, 0, stream>>>(hist, offs, cursor, NB1);
    scatter_kernel<K1, 16><<<1024, 256, 0, stream>>>(kin1, kout1, cursor, sorted);
    conv_tile<128, K1><<<NBK1, 256, 0, stream>>>(in_feats, W1, sorted, offs, up_a, statsA);
    finalize_stats<<<1, 64, 0, stream>>>(statsA, 1.f / N_UP);
    norm_elu<<<(N_UP * 64) / 256, 256, 0, stream>>>(up_a, statsA, nullptr);

    // ---- dec_block_1b: conv 3x3x3 (up_a -> up_b), CIN=64
    (void)hipMemsetAsync(hist, 0, NB1 * 4, stream);
    hist_kernel<K2, 17><<<1024, 256, 0, stream>>>(kout2, hist);
    scan_kernel<<<1, 1024, 0, stream>>>(hist, offs, cursor, NB1);
    scatter_kernel<K2, 17><<<1024, 256, 0, stream>>>(kin2, kout2, cursor, sorted);
    conv_tile<64, K2><<<NBK1, 256, 0, stream>>>(up_a, W2, sorted, offs, up_b, statsB);
    finalize_stats<<<1, 64, 0, stream>>>(statsB, 1.f / N_UP);
    norm_elu<<<(N_UP * 64) / 256, 256, 0, stream>>>(up_b, statsB, enc);  // + skip

    // ---- dec_block_2: conv k=2 (up_b -> out3), CIN=64
    (void)hipMemsetAsync(hist, 0, NB3 * 4, stream);
    hist_kernel<K3, 17><<<1024, 256, 0, stream>>>(kout3, hist);
    scan_kernel<<<1, 1024, 0, stream>>>(hist, offs, cursor, NB3);
    scatter_kernel<K3, 17><<<1024, 256, 0, stream>>>(kin3, kout3, cursor, sorted);
    conv_tile<64, K3><<<NBK3, 256, 0, stream>>>(up_b, W3, sorted, offs, out3, statsC);
    finalize_stats<<<1, 64, 0, stream>>>(statsC, 1.f / N_OUT);

    // ---- pruning head + fp32 outputs (overwrites all scratch in d_out)
    final_kernel<<<N_OUT / 4, 256, 0, stream>>>(out3, statsC, Wp, bp, outp);
}